// Round 15
// baseline (121.911 us; speedup 1.0000x reference)
//
#include <hip/hip_runtime.h>
#include <hip/hip_bf16.h>

// Problem constants: B=64, T=N=1024, d=64, k=128.

typedef __attribute__((ext_vector_type(8))) short bfrag;    // 8 x bf16 (4 VGPRs)
typedef __attribute__((ext_vector_type(4))) float ffrag;    // 4 x f32 acc

typedef const __attribute__((address_space(1))) unsigned GAS_U;
typedef __attribute__((address_space(3))) unsigned LAS_U;

#define TANH_SCALE 2.88539008177792681f   // 2*log2(e), folded into Wl/Wr/Wp

__device__ __forceinline__ void gload16(const void* g, void* l) {
  // async global->LDS, 16B per lane; LDS dest = wave-uniform base + lane*16
  __builtin_amdgcn_global_load_lds((GAS_U*)g, (LAS_U*)l, 16, 0, 0);
}

__device__ __forceinline__ unsigned short f2b(float f) {
  unsigned u = __builtin_bit_cast(unsigned, f);
  u += 0x7FFFu + ((u >> 16) & 1u);          // RNE f32 -> bf16 (finite inputs)
  return (unsigned short)(u >> 16);
}
__device__ __forceinline__ float b2f(unsigned short h) {
  return __builtin_bit_cast(float, (unsigned)h << 16);
}
// tanh with PRE-SCALED input (xs = 2*log2e*x): 1 - 2/(2^xs + 1); no v_mul
__device__ __forceinline__ float ftanhe(float xs) {
  float e = __builtin_amdgcn_exp2f(xs);
  return fmaf(-2.0f, __builtin_amdgcn_rcpf(e + 1.0f), 1.0f);
}
// packed bf16 pair {lo in low16, hi in high16}, RNE, single instruction
__device__ __forceinline__ unsigned cvtpk(float lo, float hi) {
  unsigned r;
  asm("v_cvt_pk_bf16_f32 %0, %1, %2" : "=v"(r) : "v"(lo), "v"(hi));
  return r;
}

#define MFMA(a, b, c) __builtin_amdgcn_mfma_f32_16x16x32_bf16((a), (b), (c), 0, 0, 0)

// Fragged coeff/addterm layout (K=32 slot-matched to hz's L-phase D-tiles):
//   element (k, t): tc=t>>5; c=t&31; ts'=c>>4; g=(c>>2)&3; j_c=c&3;
//                   e = ts'*4 + j_c; kt=k>>4; lr_k=k&15
//   byte = b*262144 + tc*8192 + kt*1024 + g*256 + lr_k*16 + e*2

// ---------------------------------------------------------------------------
// prep: operand-swapped GEMMs -> packed uint2 global stores.
// Wl/Wr/Wp are scaled by TANH_SCALE at load -> RWb and Rb/Pb carry the
// tanh pre-scale, so hz's tanh needs no multiply.
// ---------------------------------------------------------------------------
__global__ __launch_bounds__(256) void prep_kernel(
    const float* __restrict__ review, const float* __restrict__ post,
    const float* __restrict__ Wl, const float* __restrict__ Wr,
    const float* __restrict__ Wp,
    unsigned short* __restrict__ RWb, unsigned short* __restrict__ Rb,
    unsigned short* __restrict__ Pb, unsigned short* __restrict__ postb)
{
  const int chunk = blockIdx.x, b = blockIdx.y, side = blockIdx.z;
  const int tid = threadIdx.x, lane = tid & 63, w = tid >> 6;
  const int lr = lane & 15, lg = lane >> 4;
  const int r0 = chunk * 128;

  __shared__ __align__(16) unsigned short seqs[128][72];  // seq rows [r][d]
  __shared__ __align__(16) unsigned short wgt[128][72];   // scaled Wr/Wp [k][d]
  __shared__ __align__(16) unsigned short wlt[64][72];    // scaled Wl^T [i][d]

  const float* seq = (side == 0) ? review : post;
#pragma unroll
  for (int jj = 0; jj < 8; ++jj) {
    int e = tid + jj * 256;            // r = e>>4, d4 = (e&15)*4
    int r = e >> 4, d4 = (e & 15) * 4;
    float4 v = *(const float4*)(seq + ((size_t)(b * 1024 + r0 + r)) * 64 + d4);
    unsigned lo = ((unsigned)f2b(v.y) << 16) | f2b(v.x);
    unsigned hi = ((unsigned)f2b(v.w) << 16) | f2b(v.z);
    *(uint2*)&seqs[r][d4] = make_uint2(lo, hi);
    if (side == 1)
      *(uint2*)(postb + ((size_t)(b * 1024 + r0 + r)) * 64 + d4) = make_uint2(lo, hi);
  }
  const float* wkd = (side == 0) ? Wr : Wp;
#pragma unroll
  for (int jj = 0; jj < 8; ++jj) {
    int e = tid + jj * 256;
    int k = e >> 4, d4 = (e & 15) * 4;
    float4 v = *(const float4*)(wkd + k * 64 + d4);
    unsigned lo = ((unsigned)f2b(v.y * TANH_SCALE) << 16) | f2b(v.x * TANH_SCALE);
    unsigned hi = ((unsigned)f2b(v.w * TANH_SCALE) << 16) | f2b(v.z * TANH_SCALE);
    *(uint2*)&wgt[k][d4] = make_uint2(lo, hi);
  }
  if (side == 0) {
    for (int i = tid; i < 64 * 64; i += 256) {
      int d = i >> 6, c = i & 63;
      wlt[c][d] = f2b(Wl[d * 64 + c] * TANH_SCALE);
    }
  }
  __syncthreads();

  if (side == 0) {
    // RW^T tiles: D[i2][t], A = wlt rows, B = seqs rows.
    ffrag acc[2][4] = {};   // [tt][is]
#pragma unroll
    for (int ks = 0; ks < 2; ++ks)
#pragma unroll
      for (int is = 0; is < 4; ++is) {
        bfrag a = *(const bfrag*)&wlt[is * 16 + lr][ks * 32 + lg * 8];
#pragma unroll
        for (int tt = 0; tt < 2; ++tt) {
          bfrag bb = *(const bfrag*)&seqs[(w * 2 + tt) * 16 + lr][ks * 32 + lg * 8];
          acc[tt][is] = MFMA(a, bb, acc[tt][is]);
        }
      }
#pragma unroll
    for (int tt = 0; tt < 2; ++tt) {
      const int t = r0 + (w * 2 + tt) * 16 + lr;
      char* rowb = (char*)RWb + ((size_t)(b * 1024 + t)) * 128 + lg * 8;
#pragma unroll
      for (int is = 0; is < 4; ++is) {
        uint2 pkv;
        pkv.x = cvtpk(acc[tt][is][0], acc[tt][is][1]);
        pkv.y = cvtpk(acc[tt][is][2], acc[tt][is][3]);
        *(uint2*)(rowb + is * 32) = pkv;
      }
    }
  }
  {
    // R/P tiles: D[t][k], A = seqs rows t, B = wgt rows k -> packed e-axis.
    ffrag acc[2][8] = {};   // [tt][kt]
#pragma unroll
    for (int ks = 0; ks < 2; ++ks)
#pragma unroll
      for (int tt = 0; tt < 2; ++tt) {
        bfrag a = *(const bfrag*)&seqs[(w * 2 + tt) * 16 + lr][ks * 32 + lg * 8];
#pragma unroll
        for (int kt = 0; kt < 8; ++kt) {
          bfrag bb = *(const bfrag*)&wgt[kt * 16 + lr][ks * 32 + lg * 8];
          acc[tt][kt] = MFMA(a, bb, acc[tt][kt]);
        }
      }
    // store: tc = chunk*4 + w; ts' = tt; g = lg; lr_k = lr; e = tt*4 + j
    char* dstb = (char*)((side == 0) ? Rb : Pb) + (size_t)b * 262144
                 + (size_t)(chunk * 4 + w) * 8192 + lg * 256 + lr * 16;
#pragma unroll
    for (int tt = 0; tt < 2; ++tt)
#pragma unroll
      for (int kt = 0; kt < 8; ++kt) {
        uint2 pkv;
        pkv.x = cvtpk(acc[tt][kt][0], acc[tt][kt][1]);
        pkv.y = cvtpk(acc[tt][kt][2], acc[tt][kt][3]);
        *(uint2*)(dstb + kt * 1024 + tt * 8) = pkv;
      }
  }
}

// ---------------------------------------------------------------------------
// hz v15: r14 structure (res-32/wave, 256-thr, grid 1024) + mul-free tanh
// (scale folded in prep) + FUSED final (per-(b,role) completion counter:
// 8th finisher does softmax + weighted seq sum for its (b, side)).
// ---------------------------------------------------------------------------
__global__ __launch_bounds__(256, 4) void hz_kernel(
    const unsigned short* __restrict__ RWb, const unsigned short* __restrict__ Rb,
    const unsigned short* __restrict__ Pb, const unsigned short* __restrict__ postb,
    const float* __restrict__ whp, const float* __restrict__ whr,
    float* __restrict__ zp, float* __restrict__ zr,
    const float* __restrict__ review, const float* __restrict__ post,
    float* __restrict__ out, int* __restrict__ cnt)
{
  const int orig = blockIdx.x;
  const int swz = (orig & 7) * 128 + (orig >> 3);   // XCD-chunked, bijective
  const int strip = swz & 7, pair = swz >> 3;
  const int b = pair & 63, role = pair >> 6;
  const int s0 = strip * 128;
  const int tid = threadIdx.x, lane = tid & 63, w = tid >> 6;   // w in [0,4)
  const int lr = lane & 15, lg = lane >> 4;

  const unsigned short* resident = role ? RWb : postb;
  const unsigned short* chunkseq = role ? postb : RWb;
  const unsigned short* coeff    = role ? Pb : Rb;
  const unsigned short* addterm  = role ? Rb : Pb;
  const float* wh                = role ? whr : whp;
  float* zout                    = role ? zr : zp;

  __shared__ __align__(16) char smem[24576];
  __shared__ int winflag;
  const int woff = w << 10;   // wave-uniform LDS staging base offset

  // chunk staging source (pre-swizzled so linear dest is XOR-swizzled)
  const int crow = tid >> 3, cslot = tid & 7;
  const char* csrc = (const char*)chunkseq + (size_t)b * 131072
                     + crow * 128 + ((cslot ^ (crow & 7)) << 4);   // + tc*4096
  // coeff staging source: fragged layout == LDS layout -> pure linear
  const char* ksrc = (const char*)coeff + (size_t)b * 262144 + tid * 16; // + tc*8192

  // ---- loop-invariant resident B-frags (16 VGPRs): res = s0+w*32+rs*16+lr
  bfrag rb[2][2];   // [ks][rs]
  {
    const char* rbase = (const char*)resident + ((size_t)(b * 1024 + s0)) * 128
                        + (w * 32 + lr) * 128 + lg * 16;
#pragma unroll
    for (int rs = 0; rs < 2; ++rs) {
      rb[0][rs] = *(const bfrag*)(rbase + rs * 2048);
      rb[1][rs] = *(const bfrag*)(rbase + rs * 2048 + 64);
    }
  }

  // ---- prologue: stage chunk(0) + coeff(0) ----
  gload16(csrc, smem + woff);
  gload16(ksrc, smem + 8192 + woff);
  gload16(ksrc + 4096, smem + 8192 + 4096 + woff);
  __syncthreads();

  ffrag acc[2][8] = {};   // [rs][kt]: k = kt*16+lr, res = s0+w*32+rs*16+lg*4+j

#pragma unroll 1
  for (int tc = 0; tc < 32; ++tc) {
    const int cur = tc & 1, nb = cur ^ 1;
    // ---- issue async staging for tc+1 ----
    if (tc < 31) {
      gload16(csrc + (size_t)(tc + 1) * 4096, smem + nb * 4096 + woff);
      gload16(ksrc + (size_t)(tc + 1) * 8192, smem + 8192 + nb * 8192 + woff);
      gload16(ksrc + (size_t)(tc + 1) * 8192 + 4096,
              smem + 8192 + nb * 8192 + 4096 + woff);
    }

    // ---- L-phase(tc): D[chk32][res16] x2 rs -> tanh (mul-free) -> pk ----
    const char* rwc = smem + cur * 4096;
    uint2 pk[2][2];   // [ts][rs]
#pragma unroll
    for (int ts = 0; ts < 2; ++ts) {
      ffrag la0 = {}, la1 = {};
#pragma unroll
      for (int ks = 0; ks < 2; ++ks) {
        const int arow = ts * 16 + lr;
        bfrag a = *(const bfrag*)(rwc + arow * 128 + (((ks * 4 + lg) ^ (arow & 7)) << 4));
        la0 = MFMA(a, rb[ks][0], la0);
        la1 = MFMA(a, rb[ks][1], la1);
      }
      pk[ts][0].x = cvtpk(ftanhe(la0[0]), ftanhe(la0[1]));
      pk[ts][0].y = cvtpk(ftanhe(la0[2]), ftanhe(la0[3]));
      pk[ts][1].x = cvtpk(ftanhe(la1[0]), ftanhe(la1[1]));
      pk[ts][1].y = cvtpk(ftanhe(la1[2]), ftanhe(la1[3]));
    }
    // concatenated D-tiles == K=32 A-frags (slot-matched layout)
    uint4 a0u; a0u.x = pk[0][0].x; a0u.y = pk[0][0].y; a0u.z = pk[1][0].x; a0u.w = pk[1][0].y;
    uint4 a1u; a1u.x = pk[0][1].x; a1u.y = pk[0][1].y; a1u.z = pk[1][1].x; a1u.w = pk[1][1].y;
    const bfrag af0 = __builtin_bit_cast(bfrag, a0u);
    const bfrag af1 = __builtin_bit_cast(bfrag, a1u);

    // ---- GEMM(tc): acc[rs][kt] += L x coeff, K=32, A from registers ----
    const char* rlc = smem + 8192 + cur * 8192 + lg * 256 + lr * 16;
#pragma unroll
    for (int kt = 0; kt < 8; ++kt) {
      bfrag bk = *(const bfrag*)(rlc + kt * 1024);
      acc[0][kt] = MFMA(af0, bk, acc[0][kt]);
      acc[1][kt] = MFMA(af1, bk, acc[1][kt]);
    }
    __syncthreads();   // staging drained + buffers retired (ONE barrier/iter)
  }

  // ---- epilogue (wave-local): z[res] = sum_k wh[k] * tanh(acc + add) ----
  float whs[8];
#pragma unroll
  for (int kt = 0; kt < 8; ++kt) whs[kt] = wh[kt * 16 + lr];

  // addterm fragged read: tc_a = strip*4 + w; ts' = rs; g = lg; e = rs*4+j
  const char* abase = (const char*)addterm + (size_t)b * 262144
                      + (size_t)(strip * 4 + w) * 8192
                      + lg * 256 + lr * 16;
  float zs[2][4] = {};
#pragma unroll
  for (int rs = 0; rs < 2; ++rs)
#pragma unroll
    for (int kt = 0; kt < 8; ++kt) {
      uint2 av = *(const uint2*)(abase + kt * 1024 + rs * 8);
      const float whk = whs[kt];
      zs[rs][0] += whk * ftanhe(acc[rs][kt][0] + b2f((unsigned short)(av.x & 0xFFFF)));
      zs[rs][1] += whk * ftanhe(acc[rs][kt][1] + b2f((unsigned short)(av.x >> 16)));
      zs[rs][2] += whk * ftanhe(acc[rs][kt][2] + b2f((unsigned short)(av.y & 0xFFFF)));
      zs[rs][3] += whk * ftanhe(acc[rs][kt][3] + b2f((unsigned short)(av.y >> 16)));
    }
#pragma unroll
  for (int rs = 0; rs < 2; ++rs)
#pragma unroll
    for (int j = 0; j < 4; ++j) {
      float v = zs[rs][j];
      v += __shfl_xor(v, 1);
      v += __shfl_xor(v, 2);
      v += __shfl_xor(v, 4);
      v += __shfl_xor(v, 8);
      if (lr == 0)
        zout[(size_t)b * 1024 + s0 + w * 32 + rs * 16 + lg * 4 + j] = v;
    }

  // ---- fused final: 8th finisher for (b, role) does softmax + seq sum ----
  __syncthreads();   // each wave's z stores drained at its barrier waitcnt
  if (tid == 0) {
    __threadfence();                           // release: L2 writeback
    int old = atomicAdd(&cnt[role * 64 + b], 1);
    winflag = (old == 7);
  }
  __syncthreads();
  if (!winflag) return;
  if (tid == 0) __threadfence();               // acquire: invalidate stale
  __syncthreads();

  {
    float* zl  = (float*)smem;            // 4 KB
    float* red = (float*)(smem + 4096);   // 1 KB
    float* cac = (float*)(smem + 8192);   // 1 KB
    const float* seq = role ? review : post;

    for (int i = tid; i < 1024; i += 256) zl[i] = zout[(size_t)b * 1024 + i];
    __syncthreads();
    float m = -3.4e38f;
    for (int i = tid; i < 1024; i += 256) m = fmaxf(m, zl[i]);
    red[tid] = m;
    __syncthreads();
    for (int s = 128; s > 0; s >>= 1) {
      if (tid < s) red[tid] = fmaxf(red[tid], red[tid + s]);
      __syncthreads();
    }
    m = red[0];
    __syncthreads();
    float sm = 0.f;
    for (int i = tid; i < 1024; i += 256) {
      float e = __expf(zl[i] - m);
      zl[i] = e;
      sm += e;
    }
    red[tid] = sm;
    __syncthreads();
    for (int s = 128; s > 0; s >>= 1) {
      if (tid < s) red[tid] += red[tid + s];
      __syncthreads();
    }
    const float inv = 1.0f / red[0];
    __syncthreads();
    const int d = tid & 63, g = tid >> 6;
    float a = 0.f;
    for (int n = g * 256; n < g * 256 + 256; ++n)
      a += zl[n] * seq[((size_t)(b * 1024 + n)) * 64 + d];
    cac[g * 64 + d] = a;
    __syncthreads();
    if (tid < 64)
      out[b * 128 + role * 64 + tid] =
          (cac[tid] + cac[64 + tid] + cac[128 + tid] + cac[192 + tid]) * inv;
  }
}

// ---------------------------------------------------------------------------
extern "C" void kernel_launch(void* const* d_in, const int* in_sizes, int n_in,
                              void* d_out, int out_size, void* d_ws, size_t ws_size,
                              hipStream_t stream) {
  const float* review = (const float*)d_in[0];
  const float* post   = (const float*)d_in[1];
  const float* Wl     = (const float*)d_in[2];
  const float* Wr     = (const float*)d_in[3];
  const float* Wp     = (const float*)d_in[4];
  const float* whr    = (const float*)d_in[5];
  const float* whp    = (const float*)d_in[6];
  float* out = (float*)d_out;

  char* ws = (char*)d_ws;
  unsigned short* RWb   = (unsigned short*)(ws);                        //  8 MiB
  unsigned short* Rb    = (unsigned short*)(ws + (size_t)8  * 1048576); // 16 MiB
  unsigned short* Pb    = (unsigned short*)(ws + (size_t)24 * 1048576); // 16 MiB
  unsigned short* postb = (unsigned short*)(ws + (size_t)40 * 1048576); //  8 MiB
  float* zp = (float*)(ws + (size_t)48 * 1048576);                      // 256 KiB
  float* zr = (float*)(ws + (size_t)48 * 1048576 + 262144);             // 256 KiB
  int*   cnt = (int*)(ws + (size_t)48 * 1048576 + 524288);              // 512 B

  hipMemsetAsync(cnt, 0, 512, stream);   // reset completion counters (graph-safe)
  prep_kernel<<<dim3(8, 64, 2), dim3(256), 0, stream>>>(
      review, post, Wl, Wr, Wp, RWb, Rb, Pb, postb);
  hz_kernel<<<dim3(1024), dim3(256), 0, stream>>>(
      RWb, Rb, Pb, postb, whp, whr, zp, zr, review, post, out, cnt);
}

// Round 16
// 92.802 us; speedup vs baseline: 1.3137x; 1.3137x over previous
//
#include <hip/hip_runtime.h>
#include <hip/hip_bf16.h>

// Problem constants: B=64, T=N=1024, d=64, k=128.

typedef __attribute__((ext_vector_type(8))) short bfrag;    // 8 x bf16 (4 VGPRs)
typedef __attribute__((ext_vector_type(4))) float ffrag;    // 4 x f32 acc

typedef const __attribute__((address_space(1))) unsigned GAS_U;
typedef __attribute__((address_space(3))) unsigned LAS_U;

#define TANH_SCALE 2.88539008177792681f   // 2*log2(e), folded into Wl/Wr/Wp

__device__ __forceinline__ void gload16(const void* g, void* l) {
  // async global->LDS, 16B per lane; LDS dest = wave-uniform base + lane*16
  __builtin_amdgcn_global_load_lds((GAS_U*)g, (LAS_U*)l, 16, 0, 0);
}

__device__ __forceinline__ unsigned short f2b(float f) {
  unsigned u = __builtin_bit_cast(unsigned, f);
  u += 0x7FFFu + ((u >> 16) & 1u);          // RNE f32 -> bf16 (finite inputs)
  return (unsigned short)(u >> 16);
}
__device__ __forceinline__ float b2f(unsigned short h) {
  return __builtin_bit_cast(float, (unsigned)h << 16);
}
// tanh with PRE-SCALED input (xs = 2*log2e*x): 1 - 2/(2^xs + 1); no v_mul
__device__ __forceinline__ float ftanhe(float xs) {
  float e = __builtin_amdgcn_exp2f(xs);
  return fmaf(-2.0f, __builtin_amdgcn_rcpf(e + 1.0f), 1.0f);
}
// packed bf16 pair {lo in low16, hi in high16}, RNE, single instruction
__device__ __forceinline__ unsigned cvtpk(float lo, float hi) {
  unsigned r;
  asm("v_cvt_pk_bf16_f32 %0, %1, %2" : "=v"(r) : "v"(lo), "v"(hi));
  return r;
}

#define MFMA(a, b, c) __builtin_amdgcn_mfma_f32_16x16x32_bf16((a), (b), (c), 0, 0, 0)

// Fragged coeff/addterm layout (K=32 slot-matched to hz's L-phase D-tiles):
//   element (k, t): tc=t>>5; c=t&31; ts'=c>>4; g=(c>>2)&3; j_c=c&3;
//                   e = ts'*4 + j_c; kt=k>>4; lr_k=k&15
//   byte = b*262144 + tc*8192 + kt*1024 + g*256 + lr_k*16 + e*2

// ---------------------------------------------------------------------------
// prep: operand-swapped GEMMs -> packed uint2 global stores.
// Wl/Wr/Wp scaled by TANH_SCALE at load -> RWb and Rb/Pb carry the tanh
// pre-scale, so hz's tanh needs no multiply. (Accuracy verified in r15.)
// ---------------------------------------------------------------------------
__global__ __launch_bounds__(256) void prep_kernel(
    const float* __restrict__ review, const float* __restrict__ post,
    const float* __restrict__ Wl, const float* __restrict__ Wr,
    const float* __restrict__ Wp,
    unsigned short* __restrict__ RWb, unsigned short* __restrict__ Rb,
    unsigned short* __restrict__ Pb, unsigned short* __restrict__ postb)
{
  const int chunk = blockIdx.x, b = blockIdx.y, side = blockIdx.z;
  const int tid = threadIdx.x, lane = tid & 63, w = tid >> 6;
  const int lr = lane & 15, lg = lane >> 4;
  const int r0 = chunk * 128;

  __shared__ __align__(16) unsigned short seqs[128][72];  // seq rows [r][d]
  __shared__ __align__(16) unsigned short wgt[128][72];   // scaled Wr/Wp [k][d]
  __shared__ __align__(16) unsigned short wlt[64][72];    // scaled Wl^T [i][d]

  const float* seq = (side == 0) ? review : post;
#pragma unroll
  for (int jj = 0; jj < 8; ++jj) {
    int e = tid + jj * 256;            // r = e>>4, d4 = (e&15)*4
    int r = e >> 4, d4 = (e & 15) * 4;
    float4 v = *(const float4*)(seq + ((size_t)(b * 1024 + r0 + r)) * 64 + d4);
    unsigned lo = ((unsigned)f2b(v.y) << 16) | f2b(v.x);
    unsigned hi = ((unsigned)f2b(v.w) << 16) | f2b(v.z);
    *(uint2*)&seqs[r][d4] = make_uint2(lo, hi);
    if (side == 1)
      *(uint2*)(postb + ((size_t)(b * 1024 + r0 + r)) * 64 + d4) = make_uint2(lo, hi);
  }
  const float* wkd = (side == 0) ? Wr : Wp;
#pragma unroll
  for (int jj = 0; jj < 8; ++jj) {
    int e = tid + jj * 256;
    int k = e >> 4, d4 = (e & 15) * 4;
    float4 v = *(const float4*)(wkd + k * 64 + d4);
    unsigned lo = ((unsigned)f2b(v.y * TANH_SCALE) << 16) | f2b(v.x * TANH_SCALE);
    unsigned hi = ((unsigned)f2b(v.w * TANH_SCALE) << 16) | f2b(v.z * TANH_SCALE);
    *(uint2*)&wgt[k][d4] = make_uint2(lo, hi);
  }
  if (side == 0) {
    for (int i = tid; i < 64 * 64; i += 256) {
      int d = i >> 6, c = i & 63;
      wlt[c][d] = f2b(Wl[d * 64 + c] * TANH_SCALE);
    }
  }
  __syncthreads();

  if (side == 0) {
    // RW^T tiles: D[i2][t], A = wlt rows, B = seqs rows.
    ffrag acc[2][4] = {};   // [tt][is]
#pragma unroll
    for (int ks = 0; ks < 2; ++ks)
#pragma unroll
      for (int is = 0; is < 4; ++is) {
        bfrag a = *(const bfrag*)&wlt[is * 16 + lr][ks * 32 + lg * 8];
#pragma unroll
        for (int tt = 0; tt < 2; ++tt) {
          bfrag bb = *(const bfrag*)&seqs[(w * 2 + tt) * 16 + lr][ks * 32 + lg * 8];
          acc[tt][is] = MFMA(a, bb, acc[tt][is]);
        }
      }
#pragma unroll
    for (int tt = 0; tt < 2; ++tt) {
      const int t = r0 + (w * 2 + tt) * 16 + lr;
      char* rowb = (char*)RWb + ((size_t)(b * 1024 + t)) * 128 + lg * 8;
#pragma unroll
      for (int is = 0; is < 4; ++is) {
        uint2 pkv;
        pkv.x = cvtpk(acc[tt][is][0], acc[tt][is][1]);
        pkv.y = cvtpk(acc[tt][is][2], acc[tt][is][3]);
        *(uint2*)(rowb + is * 32) = pkv;
      }
    }
  }
  {
    // R/P tiles: D[t][k], A = seqs rows t, B = wgt rows k -> packed e-axis.
    ffrag acc[2][8] = {};   // [tt][kt]
#pragma unroll
    for (int ks = 0; ks < 2; ++ks)
#pragma unroll
      for (int tt = 0; tt < 2; ++tt) {
        bfrag a = *(const bfrag*)&seqs[(w * 2 + tt) * 16 + lr][ks * 32 + lg * 8];
#pragma unroll
        for (int kt = 0; kt < 8; ++kt) {
          bfrag bb = *(const bfrag*)&wgt[kt * 16 + lr][ks * 32 + lg * 8];
          acc[tt][kt] = MFMA(a, bb, acc[tt][kt]);
        }
      }
    // store: tc = chunk*4 + w; ts' = tt; g = lg; lr_k = lr; e = tt*4 + j
    char* dstb = (char*)((side == 0) ? Rb : Pb) + (size_t)b * 262144
                 + (size_t)(chunk * 4 + w) * 8192 + lg * 256 + lr * 16;
#pragma unroll
    for (int tt = 0; tt < 2; ++tt)
#pragma unroll
      for (int kt = 0; kt < 8; ++kt) {
        uint2 pkv;
        pkv.x = cvtpk(acc[tt][kt][0], acc[tt][kt][1]);
        pkv.y = cvtpk(acc[tt][kt][2], acc[tt][kt][3]);
        *(uint2*)(dstb + kt * 1024 + tt * 8) = pkv;
      }
  }
}

// ---------------------------------------------------------------------------
// hz v16 = r13 structure (best measured: 68.9 us) + mul-free tanh.
// 512-thread blocks (8 waves), wave owns res-32 x all 128 k; strip res-256;
// grid 512. Register-direct K=32 L feed (slot-matched), ONE barrier/iter.
// LDS (24576 B): rw dbuf @0/@4096 [32 rows][128B] chunk (pre-swz global src)
//                rl dbuf @8192/@16384 fragged coeff (LINEAR gload src)
// ---------------------------------------------------------------------------
__global__ __launch_bounds__(512, 4) void hz_kernel(
    const unsigned short* __restrict__ RWb, const unsigned short* __restrict__ Rb,
    const unsigned short* __restrict__ Pb, const unsigned short* __restrict__ postb,
    const float* __restrict__ whp, const float* __restrict__ whr,
    float* __restrict__ zp, float* __restrict__ zr)
{
  const int orig = blockIdx.x;
  const int swz = (orig & 7) * 64 + (orig >> 3);   // XCD-chunked, 512 = 8*64
  const int strip = swz & 3, pair = swz >> 2;
  const int b = pair & 63, role = pair >> 6;
  const int s0 = strip * 256;
  const int tid = threadIdx.x, lane = tid & 63, w = tid >> 6;
  const int lr = lane & 15, lg = lane >> 4;

  const unsigned short* resident = role ? RWb : postb;
  const unsigned short* chunkseq = role ? postb : RWb;
  const unsigned short* coeff    = role ? Pb : Rb;
  const unsigned short* addterm  = role ? Rb : Pb;
  const float* wh                = role ? whr : whp;
  float* zout                    = role ? zr : zp;

  __shared__ __align__(16) char smem[24576];
  const int woff = w << 10;   // wave-uniform LDS staging base offset

  // chunk staging source (pre-swizzled so linear dest is XOR-swizzled);
  // waves 0-3 issue (4KB per tc)
  const int crow = tid >> 3, cslot = tid & 7;
  const char* csrc = (const char*)chunkseq + (size_t)b * 131072
                     + crow * 128 + ((cslot ^ (crow & 7)) << 4);   // + tc*4096
  // coeff staging source: fragged layout == LDS layout -> pure linear,
  // all 8 waves (8KB per tc)
  const char* ksrc = (const char*)coeff + (size_t)b * 262144 + tid * 16; // + tc*8192

  // ---- loop-invariant resident B-frags (16 VGPRs): res = s0+w*32+rs*16+lr
  bfrag rb[2][2];   // [ks][rs]
  {
    const char* rbase = (const char*)resident + ((size_t)(b * 1024 + s0)) * 128
                        + (w * 32 + lr) * 128 + lg * 16;
#pragma unroll
    for (int rs = 0; rs < 2; ++rs) {
      rb[0][rs] = *(const bfrag*)(rbase + rs * 2048);
      rb[1][rs] = *(const bfrag*)(rbase + rs * 2048 + 64);
    }
  }

  // ---- prologue: stage chunk(0) + coeff(0) ----
  if (w < 4) gload16(csrc, smem + woff);
  gload16(ksrc, smem + 8192 + woff);
  __syncthreads();

  ffrag acc[2][8] = {};   // [rs][kt]: k = kt*16+lr, res = s0+w*32+rs*16+lg*4+j

#pragma unroll 1
  for (int tc = 0; tc < 32; ++tc) {
    const int cur = tc & 1, nb = cur ^ 1;
    // ---- issue async staging for tc+1 ----
    if (tc < 31) {
      if (w < 4) gload16(csrc + (size_t)(tc + 1) * 4096, smem + nb * 4096 + woff);
      gload16(ksrc + (size_t)(tc + 1) * 8192, smem + 8192 + nb * 8192 + woff);
    }

    // ---- L-phase(tc): D[chk32][res16] x2 rs -> tanh (mul-free) -> pk ----
    const char* rwc = smem + cur * 4096;
    uint2 pk[2][2];   // [ts][rs]
#pragma unroll
    for (int ts = 0; ts < 2; ++ts) {
      ffrag la0 = {}, la1 = {};
#pragma unroll
      for (int ks = 0; ks < 2; ++ks) {
        const int arow = ts * 16 + lr;
        bfrag a = *(const bfrag*)(rwc + arow * 128 + (((ks * 4 + lg) ^ (arow & 7)) << 4));
        la0 = MFMA(a, rb[ks][0], la0);
        la1 = MFMA(a, rb[ks][1], la1);
      }
      pk[ts][0].x = cvtpk(ftanhe(la0[0]), ftanhe(la0[1]));
      pk[ts][0].y = cvtpk(ftanhe(la0[2]), ftanhe(la0[3]));
      pk[ts][1].x = cvtpk(ftanhe(la1[0]), ftanhe(la1[1]));
      pk[ts][1].y = cvtpk(ftanhe(la1[2]), ftanhe(la1[3]));
    }
    // concatenated D-tiles == K=32 A-frags (slot-matched layout)
    uint4 a0u; a0u.x = pk[0][0].x; a0u.y = pk[0][0].y; a0u.z = pk[1][0].x; a0u.w = pk[1][0].y;
    uint4 a1u; a1u.x = pk[0][1].x; a1u.y = pk[0][1].y; a1u.z = pk[1][1].x; a1u.w = pk[1][1].y;
    const bfrag af0 = __builtin_bit_cast(bfrag, a0u);
    const bfrag af1 = __builtin_bit_cast(bfrag, a1u);

    // ---- GEMM(tc): acc[rs][kt] += L x coeff, K=32, A from registers ----
    const char* rlc = smem + 8192 + cur * 8192 + lg * 256 + lr * 16;
#pragma unroll
    for (int kt = 0; kt < 8; ++kt) {
      bfrag bk = *(const bfrag*)(rlc + kt * 1024);
      acc[0][kt] = MFMA(af0, bk, acc[0][kt]);
      acc[1][kt] = MFMA(af1, bk, acc[1][kt]);
    }
    __syncthreads();   // staging drained + buffers retired (ONE barrier/iter)
  }

  // ---- epilogue (wave-local): z[res] = sum_k wh[k] * tanh(acc + add) ----
  float whs[8];
#pragma unroll
  for (int kt = 0; kt < 8; ++kt) whs[kt] = wh[kt * 16 + lr];

  // addterm fragged read: tc_a = strip*8 + w; ts' = rs; g = lg; e = rs*4+j
  const char* abase = (const char*)addterm + (size_t)b * 262144
                      + (size_t)(strip * 8 + w) * 8192
                      + lg * 256 + lr * 16;
  float zs[2][4] = {};
#pragma unroll
  for (int rs = 0; rs < 2; ++rs)
#pragma unroll
    for (int kt = 0; kt < 8; ++kt) {
      uint2 av = *(const uint2*)(abase + kt * 1024 + rs * 8);
      const float whk = whs[kt];
      zs[rs][0] += whk * ftanhe(acc[rs][kt][0] + b2f((unsigned short)(av.x & 0xFFFF)));
      zs[rs][1] += whk * ftanhe(acc[rs][kt][1] + b2f((unsigned short)(av.x >> 16)));
      zs[rs][2] += whk * ftanhe(acc[rs][kt][2] + b2f((unsigned short)(av.y & 0xFFFF)));
      zs[rs][3] += whk * ftanhe(acc[rs][kt][3] + b2f((unsigned short)(av.y >> 16)));
    }
#pragma unroll
  for (int rs = 0; rs < 2; ++rs)
#pragma unroll
    for (int j = 0; j < 4; ++j) {
      float v = zs[rs][j];
      v += __shfl_xor(v, 1);
      v += __shfl_xor(v, 2);
      v += __shfl_xor(v, 4);
      v += __shfl_xor(v, 8);
      if (lr == 0)
        zout[(size_t)b * 1024 + s0 + w * 32 + rs * 16 + lg * 4 + j] = v;
    }
}

// ---------------------------------------------------------------------------
// final: block (b, side), 1024 threads: softmax(z) -> weighted seq sum -> out
// ---------------------------------------------------------------------------
__global__ __launch_bounds__(1024) void final_kernel(
    const float* __restrict__ review, const float* __restrict__ post,
    const float* __restrict__ zp, const float* __restrict__ zr,
    float* __restrict__ out)
{
  const int b = blockIdx.x, side = blockIdx.y, tid = threadIdx.x;
  const int wid = tid >> 6, lane = tid & 63;
  __shared__ float zl[1024];
  __shared__ float red[16];
  __shared__ float cacc[16][64];

  const float* z = (side == 0) ? zp : zr;
  const float* seq = (side == 0) ? post : review;

  float v = z[(size_t)b * 1024 + tid];
  zl[tid] = v;
  float m = v;
#pragma unroll
  for (int off = 32; off; off >>= 1) m = fmaxf(m, __shfl_xor(m, off));
  if (lane == 0) red[wid] = m;
  __syncthreads();
  m = red[0];
#pragma unroll
  for (int i = 1; i < 16; ++i) m = fmaxf(m, red[i]);
  __syncthreads();

  float e = __expf(v - m);
  zl[tid] = e;
  float sm = e;
#pragma unroll
  for (int off = 32; off; off >>= 1) sm += __shfl_xor(sm, off);
  if (lane == 0) red[wid] = sm;
  __syncthreads();
  sm = red[0];
#pragma unroll
  for (int i = 1; i < 16; ++i) sm += red[i];
  const float inv = 1.0f / sm;

  const int d = lane;
  float a = 0.f;
  for (int n = wid * 64; n < wid * 64 + 64; ++n)
    a += zl[n] * seq[((size_t)(b * 1024 + n)) * 64 + d];
  cacc[wid][d] = a;
  __syncthreads();
  if (tid < 64) {
    float s = 0.f;
#pragma unroll
    for (int g = 0; g < 16; ++g) s += cacc[g][tid];
    out[b * 128 + side * 64 + tid] = s * inv;
  }
}

// ---------------------------------------------------------------------------
extern "C" void kernel_launch(void* const* d_in, const int* in_sizes, int n_in,
                              void* d_out, int out_size, void* d_ws, size_t ws_size,
                              hipStream_t stream) {
  const float* review = (const float*)d_in[0];
  const float* post   = (const float*)d_in[1];
  const float* Wl     = (const float*)d_in[2];
  const float* Wr     = (const float*)d_in[3];
  const float* Wp     = (const float*)d_in[4];
  const float* whr    = (const float*)d_in[5];
  const float* whp    = (const float*)d_in[6];
  float* out = (float*)d_out;

  char* ws = (char*)d_ws;
  unsigned short* RWb   = (unsigned short*)(ws);                        //  8 MiB
  unsigned short* Rb    = (unsigned short*)(ws + (size_t)8  * 1048576); // 16 MiB
  unsigned short* Pb    = (unsigned short*)(ws + (size_t)24 * 1048576); // 16 MiB
  unsigned short* postb = (unsigned short*)(ws + (size_t)40 * 1048576); //  8 MiB
  float* zp = (float*)(ws + (size_t)48 * 1048576);                      // 256 KiB
  float* zr = (float*)(ws + (size_t)48 * 1048576 + 262144);             // 256 KiB

  prep_kernel<<<dim3(8, 64, 2), dim3(256), 0, stream>>>(
      review, post, Wl, Wr, Wp, RWb, Rb, Pb, postb);
  hz_kernel<<<dim3(512), dim3(512), 0, stream>>>(
      RWb, Rb, Pb, postb, whp, whr, zp, zr);
  final_kernel<<<dim3(64, 2), dim3(1024), 0, stream>>>(
      review, post, zp, zr, out);
}

// Round 17
// 91.324 us; speedup vs baseline: 1.3349x; 1.0162x over previous
//
#include <hip/hip_runtime.h>
#include <hip/hip_bf16.h>

// Problem constants: B=64, T=N=1024, d=64, k=128.

typedef __attribute__((ext_vector_type(8))) short bfrag;    // 8 x bf16 (4 VGPRs)
typedef __attribute__((ext_vector_type(4))) float ffrag;    // 4 x f32 acc

typedef const __attribute__((address_space(1))) unsigned GAS_U;
typedef __attribute__((address_space(3))) unsigned LAS_U;

#define TANH_SCALE 2.88539008177792681f   // 2*log2(e), folded into Wl/Wr/Wp

__device__ __forceinline__ void gload16(const void* g, void* l) {
  // async global->LDS, 16B per lane; LDS dest = wave-uniform base + lane*16
  __builtin_amdgcn_global_load_lds((GAS_U*)g, (LAS_U*)l, 16, 0, 0);
}

__device__ __forceinline__ unsigned short f2b(float f) {
  unsigned u = __builtin_bit_cast(unsigned, f);
  u += 0x7FFFu + ((u >> 16) & 1u);          // RNE f32 -> bf16 (finite inputs)
  return (unsigned short)(u >> 16);
}
__device__ __forceinline__ float b2f(unsigned short h) {
  return __builtin_bit_cast(float, (unsigned)h << 16);
}
// tanh with PRE-SCALED input (xs = 2*log2e*x): 1 - 2/(2^xs + 1); no v_mul
__device__ __forceinline__ float ftanhe(float xs) {
  float e = __builtin_amdgcn_exp2f(xs);
  return fmaf(-2.0f, __builtin_amdgcn_rcpf(e + 1.0f), 1.0f);
}
// packed bf16 pair {lo in low16, hi in high16}, RNE, single instruction
__device__ __forceinline__ unsigned cvtpk(float lo, float hi) {
  unsigned r;
  asm("v_cvt_pk_bf16_f32 %0, %1, %2" : "=v"(r) : "v"(lo), "v"(hi));
  return r;
}

#define MFMA(a, b, c) __builtin_amdgcn_mfma_f32_16x16x32_bf16((a), (b), (c), 0, 0, 0)

// Fragged coeff/addterm layout (K=32 slot-matched to hz's L-phase D-tiles):
//   element (k, t): tc=t>>5; c=t&31; ts'=c>>4; g=(c>>2)&3; j_c=c&3;
//                   e = ts'*4 + j_c; kt=k>>4; lr_k=k&15
//   byte = b*262144 + tc*8192 + kt*1024 + g*256 + lr_k*16 + e*2

// ---------------------------------------------------------------------------
// prep (unchanged from r16): operand-swapped GEMMs -> packed uint2 stores;
// Wl/Wr/Wp carry TANH_SCALE.
// ---------------------------------------------------------------------------
__global__ __launch_bounds__(256) void prep_kernel(
    const float* __restrict__ review, const float* __restrict__ post,
    const float* __restrict__ Wl, const float* __restrict__ Wr,
    const float* __restrict__ Wp,
    unsigned short* __restrict__ RWb, unsigned short* __restrict__ Rb,
    unsigned short* __restrict__ Pb, unsigned short* __restrict__ postb)
{
  const int chunk = blockIdx.x, b = blockIdx.y, side = blockIdx.z;
  const int tid = threadIdx.x, lane = tid & 63, w = tid >> 6;
  const int lr = lane & 15, lg = lane >> 4;
  const int r0 = chunk * 128;

  __shared__ __align__(16) unsigned short seqs[128][72];  // seq rows [r][d]
  __shared__ __align__(16) unsigned short wgt[128][72];   // scaled Wr/Wp [k][d]
  __shared__ __align__(16) unsigned short wlt[64][72];    // scaled Wl^T [i][d]

  const float* seq = (side == 0) ? review : post;
#pragma unroll
  for (int jj = 0; jj < 8; ++jj) {
    int e = tid + jj * 256;            // r = e>>4, d4 = (e&15)*4
    int r = e >> 4, d4 = (e & 15) * 4;
    float4 v = *(const float4*)(seq + ((size_t)(b * 1024 + r0 + r)) * 64 + d4);
    unsigned lo = ((unsigned)f2b(v.y) << 16) | f2b(v.x);
    unsigned hi = ((unsigned)f2b(v.w) << 16) | f2b(v.z);
    *(uint2*)&seqs[r][d4] = make_uint2(lo, hi);
    if (side == 1)
      *(uint2*)(postb + ((size_t)(b * 1024 + r0 + r)) * 64 + d4) = make_uint2(lo, hi);
  }
  const float* wkd = (side == 0) ? Wr : Wp;
#pragma unroll
  for (int jj = 0; jj < 8; ++jj) {
    int e = tid + jj * 256;
    int k = e >> 4, d4 = (e & 15) * 4;
    float4 v = *(const float4*)(wkd + k * 64 + d4);
    unsigned lo = ((unsigned)f2b(v.y * TANH_SCALE) << 16) | f2b(v.x * TANH_SCALE);
    unsigned hi = ((unsigned)f2b(v.w * TANH_SCALE) << 16) | f2b(v.z * TANH_SCALE);
    *(uint2*)&wgt[k][d4] = make_uint2(lo, hi);
  }
  if (side == 0) {
    for (int i = tid; i < 64 * 64; i += 256) {
      int d = i >> 6, c = i & 63;
      wlt[c][d] = f2b(Wl[d * 64 + c] * TANH_SCALE);
    }
  }
  __syncthreads();

  if (side == 0) {
    // RW^T tiles: D[i2][t], A = wlt rows, B = seqs rows.
    ffrag acc[2][4] = {};   // [tt][is]
#pragma unroll
    for (int ks = 0; ks < 2; ++ks)
#pragma unroll
      for (int is = 0; is < 4; ++is) {
        bfrag a = *(const bfrag*)&wlt[is * 16 + lr][ks * 32 + lg * 8];
#pragma unroll
        for (int tt = 0; tt < 2; ++tt) {
          bfrag bb = *(const bfrag*)&seqs[(w * 2 + tt) * 16 + lr][ks * 32 + lg * 8];
          acc[tt][is] = MFMA(a, bb, acc[tt][is]);
        }
      }
#pragma unroll
    for (int tt = 0; tt < 2; ++tt) {
      const int t = r0 + (w * 2 + tt) * 16 + lr;
      char* rowb = (char*)RWb + ((size_t)(b * 1024 + t)) * 128 + lg * 8;
#pragma unroll
      for (int is = 0; is < 4; ++is) {
        uint2 pkv;
        pkv.x = cvtpk(acc[tt][is][0], acc[tt][is][1]);
        pkv.y = cvtpk(acc[tt][is][2], acc[tt][is][3]);
        *(uint2*)(rowb + is * 32) = pkv;
      }
    }
  }
  {
    // R/P tiles: D[t][k], A = seqs rows t, B = wgt rows k -> packed e-axis.
    ffrag acc[2][8] = {};   // [tt][kt]
#pragma unroll
    for (int ks = 0; ks < 2; ++ks)
#pragma unroll
      for (int tt = 0; tt < 2; ++tt) {
        bfrag a = *(const bfrag*)&seqs[(w * 2 + tt) * 16 + lr][ks * 32 + lg * 8];
#pragma unroll
        for (int kt = 0; kt < 8; ++kt) {
          bfrag bb = *(const bfrag*)&wgt[kt * 16 + lr][ks * 32 + lg * 8];
          acc[tt][kt] = MFMA(a, bb, acc[tt][kt]);
        }
      }
    // store: tc = chunk*4 + w; ts' = tt; g = lg; lr_k = lr; e = tt*4 + j
    char* dstb = (char*)((side == 0) ? Rb : Pb) + (size_t)b * 262144
                 + (size_t)(chunk * 4 + w) * 8192 + lg * 256 + lr * 16;
#pragma unroll
    for (int tt = 0; tt < 2; ++tt)
#pragma unroll
      for (int kt = 0; kt < 8; ++kt) {
        uint2 pkv;
        pkv.x = cvtpk(acc[tt][kt][0], acc[tt][kt][1]);
        pkv.y = cvtpk(acc[tt][kt][2], acc[tt][kt][3]);
        *(uint2*)(dstb + kt * 1024 + tt * 8) = pkv;
      }
  }
}

// ---------------------------------------------------------------------------
// hz v17 = r16 compute body + SEGMENT-2 quad-buffered staging:
// 2 K-steps per __syncthreads (17 barriers vs 33), loads for segment s+1
// issued at top of segment s -> 2 iterations of latency coverage.
// 512-thread blocks (8 waves), wave owns res-32 x all 128 k; strip res-256;
// grid 512 (2 blocks/CU).
// LDS (49152 B): rw [seg][step] @ seg*8192+step*4096   (16 KB)
//                rl [seg][step] @ 16384+seg*16384+step*8192 (32 KB)
// Chunk staging: wave-group g = w>>2 stages step g (256 thr = 4 KB each).
// Coeff staging: all 512 threads, 2 gload16 each (16 KB per segment).
// ---------------------------------------------------------------------------
__global__ __launch_bounds__(512, 4) void hz_kernel(
    const unsigned short* __restrict__ RWb, const unsigned short* __restrict__ Rb,
    const unsigned short* __restrict__ Pb, const unsigned short* __restrict__ postb,
    const float* __restrict__ whp, const float* __restrict__ whr,
    float* __restrict__ zp, float* __restrict__ zr)
{
  const int orig = blockIdx.x;
  const int swz = (orig & 7) * 64 + (orig >> 3);   // XCD-chunked, 512 = 8*64
  const int strip = swz & 3, pair = swz >> 2;
  const int b = pair & 63, role = pair >> 6;
  const int s0 = strip * 256;
  const int tid = threadIdx.x, lane = tid & 63, w = tid >> 6;
  const int lr = lane & 15, lg = lane >> 4;

  const unsigned short* resident = role ? RWb : postb;
  const unsigned short* chunkseq = role ? postb : RWb;
  const unsigned short* coeff    = role ? Pb : Rb;
  const unsigned short* addterm  = role ? Rb : Pb;
  const float* wh                = role ? whr : whp;
  float* zout                    = role ? zr : zp;

  __shared__ __align__(16) char smem[49152];

  // chunk staging: group g = w>>2 stages step g; within-group mapping uses
  // ct = (w&3)*64 + lane (same swizzled-source formula as r16)
  const int g = w >> 2, wg = w & 3;
  const int crow = wg * 8 + (lane >> 3), cslot = lane & 7;
  const char* csrc = (const char*)chunkseq + (size_t)b * 131072
                     + crow * 128 + ((cslot ^ (crow & 7)) << 4);   // + tc*4096
  // coeff staging: fragged layout == LDS layout -> pure linear
  const char* ksrc = (const char*)coeff + (size_t)b * 262144 + tid * 16; // + tc*8192

  // ---- loop-invariant resident B-frags (16 VGPRs): res = s0+w*32+rs*16+lr
  bfrag rb[2][2];   // [ks][rs]
  {
    const char* rbase = (const char*)resident + ((size_t)(b * 1024 + s0)) * 128
                        + (w * 32 + lr) * 128 + lg * 16;
#pragma unroll
    for (int rs = 0; rs < 2; ++rs) {
      rb[0][rs] = *(const bfrag*)(rbase + rs * 2048);
      rb[1][rs] = *(const bfrag*)(rbase + rs * 2048 + 64);
    }
  }

  // ---- prologue: stage segment 0 (tc = 0,1) into segbuf 0 ----
  gload16(csrc + g * 4096, smem + g * 4096 + wg * 1024);
  gload16(ksrc,            smem + 16384 + w * 1024);
  gload16(ksrc + 8192,     smem + 16384 + 8192 + w * 1024);
  __syncthreads();

  ffrag acc[2][8] = {};   // [rs][kt]: k = kt*16+lr, res = s0+w*32+rs*16+lg*4+j

#pragma unroll 1
  for (int seg = 0; seg < 16; ++seg) {
    const int cur = seg & 1, nb = cur ^ 1;
    // ---- issue async staging for segment seg+1 (2 chunks + 2 coeffs) ----
    if (seg < 15) {
      const size_t co = (size_t)(2 * (seg + 1)) * 4096;
      const size_t ko = (size_t)(2 * (seg + 1)) * 8192;
      gload16(csrc + co + g * 4096, smem + nb * 8192 + g * 4096 + wg * 1024);
      gload16(ksrc + ko,            smem + 16384 + nb * 16384 + w * 1024);
      gload16(ksrc + ko + 8192,     smem + 16384 + nb * 16384 + 8192 + w * 1024);
    }

#pragma unroll
    for (int st = 0; st < 2; ++st) {
      // ---- L-phase: D[chk32][res16] x2 rs -> tanh (mul-free) -> pk ----
      const char* rwc = smem + cur * 8192 + st * 4096;
      uint2 pk[2][2];   // [ts][rs]
#pragma unroll
      for (int ts = 0; ts < 2; ++ts) {
        ffrag la0 = {}, la1 = {};
#pragma unroll
        for (int ks = 0; ks < 2; ++ks) {
          const int arow = ts * 16 + lr;
          bfrag a = *(const bfrag*)(rwc + arow * 128 + (((ks * 4 + lg) ^ (arow & 7)) << 4));
          la0 = MFMA(a, rb[ks][0], la0);
          la1 = MFMA(a, rb[ks][1], la1);
        }
        pk[ts][0].x = cvtpk(ftanhe(la0[0]), ftanhe(la0[1]));
        pk[ts][0].y = cvtpk(ftanhe(la0[2]), ftanhe(la0[3]));
        pk[ts][1].x = cvtpk(ftanhe(la1[0]), ftanhe(la1[1]));
        pk[ts][1].y = cvtpk(ftanhe(la1[2]), ftanhe(la1[3]));
      }
      // concatenated D-tiles == K=32 A-frags (slot-matched layout)
      uint4 a0u; a0u.x = pk[0][0].x; a0u.y = pk[0][0].y; a0u.z = pk[1][0].x; a0u.w = pk[1][0].y;
      uint4 a1u; a1u.x = pk[0][1].x; a1u.y = pk[0][1].y; a1u.z = pk[1][1].x; a1u.w = pk[1][1].y;
      const bfrag af0 = __builtin_bit_cast(bfrag, a0u);
      const bfrag af1 = __builtin_bit_cast(bfrag, a1u);

      // ---- GEMM: acc[rs][kt] += L x coeff, K=32, A from registers ----
      const char* rlc = smem + 16384 + cur * 16384 + st * 8192 + lg * 256 + lr * 16;
#pragma unroll
      for (int kt = 0; kt < 8; ++kt) {
        bfrag bk = *(const bfrag*)(rlc + kt * 1024);
        acc[0][kt] = MFMA(af0, bk, acc[0][kt]);
        acc[1][kt] = MFMA(af1, bk, acc[1][kt]);
      }
    }
    __syncthreads();   // seg+1 staging drained; segbuf cur retired
  }

  // ---- epilogue (wave-local): z[res] = sum_k wh[k] * tanh(acc + add) ----
  float whs[8];
#pragma unroll
  for (int kt = 0; kt < 8; ++kt) whs[kt] = wh[kt * 16 + lr];

  // addterm fragged read: tc_a = strip*8 + w; ts' = rs; g = lg; e = rs*4+j
  const char* abase = (const char*)addterm + (size_t)b * 262144
                      + (size_t)(strip * 8 + w) * 8192
                      + lg * 256 + lr * 16;
  float zs[2][4] = {};
#pragma unroll
  for (int rs = 0; rs < 2; ++rs)
#pragma unroll
    for (int kt = 0; kt < 8; ++kt) {
      uint2 av = *(const uint2*)(abase + kt * 1024 + rs * 8);
      const float whk = whs[kt];
      zs[rs][0] += whk * ftanhe(acc[rs][kt][0] + b2f((unsigned short)(av.x & 0xFFFF)));
      zs[rs][1] += whk * ftanhe(acc[rs][kt][1] + b2f((unsigned short)(av.x >> 16)));
      zs[rs][2] += whk * ftanhe(acc[rs][kt][2] + b2f((unsigned short)(av.y & 0xFFFF)));
      zs[rs][3] += whk * ftanhe(acc[rs][kt][3] + b2f((unsigned short)(av.y >> 16)));
    }
#pragma unroll
  for (int rs = 0; rs < 2; ++rs)
#pragma unroll
    for (int j = 0; j < 4; ++j) {
      float v = zs[rs][j];
      v += __shfl_xor(v, 1);
      v += __shfl_xor(v, 2);
      v += __shfl_xor(v, 4);
      v += __shfl_xor(v, 8);
      if (lr == 0)
        zout[(size_t)b * 1024 + s0 + w * 32 + rs * 16 + lg * 4 + j] = v;
    }
}

// ---------------------------------------------------------------------------
// final: block (b, side), 1024 threads: softmax(z) -> weighted seq sum -> out
// ---------------------------------------------------------------------------
__global__ __launch_bounds__(1024) void final_kernel(
    const float* __restrict__ review, const float* __restrict__ post,
    const float* __restrict__ zp, const float* __restrict__ zr,
    float* __restrict__ out)
{
  const int b = blockIdx.x, side = blockIdx.y, tid = threadIdx.x;
  const int wid = tid >> 6, lane = tid & 63;
  __shared__ float zl[1024];
  __shared__ float red[16];
  __shared__ float cacc[16][64];

  const float* z = (side == 0) ? zp : zr;
  const float* seq = (side == 0) ? post : review;

  float v = z[(size_t)b * 1024 + tid];
  zl[tid] = v;
  float m = v;
#pragma unroll
  for (int off = 32; off; off >>= 1) m = fmaxf(m, __shfl_xor(m, off));
  if (lane == 0) red[wid] = m;
  __syncthreads();
  m = red[0];
#pragma unroll
  for (int i = 1; i < 16; ++i) m = fmaxf(m, red[i]);
  __syncthreads();

  float e = __expf(v - m);
  zl[tid] = e;
  float sm = e;
#pragma unroll
  for (int off = 32; off; off >>= 1) sm += __shfl_xor(sm, off);
  if (lane == 0) red[wid] = sm;
  __syncthreads();
  sm = red[0];
#pragma unroll
  for (int i = 1; i < 16; ++i) sm += red[i];
  const float inv = 1.0f / sm;

  const int d = lane;
  float a = 0.f;
  for (int n = wid * 64; n < wid * 64 + 64; ++n)
    a += zl[n] * seq[((size_t)(b * 1024 + n)) * 64 + d];
  cacc[wid][d] = a;
  __syncthreads();
  if (tid < 64) {
    float s = 0.f;
#pragma unroll
    for (int g = 0; g < 16; ++g) s += cacc[g][tid];
    out[b * 128 + side * 64 + tid] = s * inv;
  }
}

// ---------------------------------------------------------------------------
extern "C" void kernel_launch(void* const* d_in, const int* in_sizes, int n_in,
                              void* d_out, int out_size, void* d_ws, size_t ws_size,
                              hipStream_t stream) {
  const float* review = (const float*)d_in[0];
  const float* post   = (const float*)d_in[1];
  const float* Wl     = (const float*)d_in[2];
  const float* Wr     = (const float*)d_in[3];
  const float* Wp     = (const float*)d_in[4];
  const float* whr    = (const float*)d_in[5];
  const float* whp    = (const float*)d_in[6];
  float* out = (float*)d_out;

  char* ws = (char*)d_ws;
  unsigned short* RWb   = (unsigned short*)(ws);                        //  8 MiB
  unsigned short* Rb    = (unsigned short*)(ws + (size_t)8  * 1048576); // 16 MiB
  unsigned short* Pb    = (unsigned short*)(ws + (size_t)24 * 1048576); // 16 MiB
  unsigned short* postb = (unsigned short*)(ws + (size_t)40 * 1048576); //  8 MiB
  float* zp = (float*)(ws + (size_t)48 * 1048576);                      // 256 KiB
  float* zr = (float*)(ws + (size_t)48 * 1048576 + 262144);             // 256 KiB

  prep_kernel<<<dim3(8, 64, 2), dim3(256), 0, stream>>>(
      review, post, Wl, Wr, Wp, RWb, Rb, Pb, postb);
  hz_kernel<<<dim3(512), dim3(512), 0, stream>>>(
      RWb, Rb, Pb, postb, whp, whr, zp, zr);
  final_kernel<<<dim3(64, 2), dim3(1024), 0, stream>>>(
      review, post, zp, zr, out);
}